// Round 1
// baseline (265.643 us; speedup 1.0000x reference)
//
#include <hip/hip_runtime.h>
#include <math.h>

// TripletAttention. x:[32,256,56,56] f32.
// out[b,c,h,w] = x * (s1[b,c,w] + s2[b,h,c] + s3[b,h,w]) / 3

#define B_ 32
#define C_ 256
#define H_ 56
#define W_ 56
#define HW_ 3136
#define LDSW 60            // padded LDS row stride (words); %4==0 keeps float4 stores aligned
#define CG 8               // channels per pool block
#define NGRP (C_ / CG)     // 32 channel-groups

__device__ __forceinline__ float4 f4max(float4 a, float4 b) {
    return make_float4(fmaxf(a.x, b.x), fmaxf(a.y, b.y), fmaxf(a.z, b.z), fmaxf(a.w, b.w));
}
__device__ __forceinline__ float4 f4add(float4 a, float4 b) {
    return make_float4(a.x + b.x, a.y + b.y, a.z + b.z, a.w + b.w);
}

// ---------------- Kernel 1: single pass over x ----------------
// grid = B_*NGRP blocks of 256. Each block streams CG=8 planes of one (b, c-group):
//   - per plane: stage to LDS -> row pool (P2) + col pool (P1)
//   - across planes: register max/sum accumulators -> one c-pool partial (P3p)
// Next plane's loads are issued before the current plane's reduce so HBM latency
// hides under the LDS phase.
__global__ __launch_bounds__(256) void pool_fused(const float* __restrict__ x,
                                                  float* __restrict__ P1,    // [B][2][C][W]
                                                  float* __restrict__ P2,    // [B][2][H][C]
                                                  float* __restrict__ P3p) { // [B][NGRP][2][HW]
    __shared__ float smem[H_ * LDSW];
    const int t = threadIdx.x;
    const int b = blockIdx.x >> 5;            // / NGRP
    const int g = blockIdx.x & (NGRP - 1);
    const int c0 = g * CG;
    const float* __restrict__ base = x + (size_t)(b * C_ + c0) * HW_;

    // float4-slot ownership: t, t+256, t+512, (t<16: t+768); 784 slots = one plane.
    const int s0 = t, s1i = t + 256, s2i = t + 512, s3i = t + 768;
    const int h0 = s0 / 14,  ad0 = h0 * LDSW + (s0 - h0 * 14) * 4;
    const int h1 = s1i / 14, ad1 = h1 * LDSW + (s1i - h1 * 14) * 4;
    const int h2 = s2i / 14, ad2 = h2 * LDSW + (s2i - h2 * 14) * 4;
    const int h3 = s3i / 14, ad3 = h3 * LDSW + (s3i - h3 * 14) * 4;

    float4 mx0, mx1, mx2, mx3, su0, su1, su2, su3;
    mx0 = mx1 = mx2 = mx3 = make_float4(-INFINITY, -INFINITY, -INFINITY, -INFINITY);
    su0 = su1 = su2 = su3 = make_float4(0.f, 0.f, 0.f, 0.f);

    const float4* bp = (const float4*)base;
    float4 cur0 = bp[s0], cur1 = bp[s1i], cur2 = bp[s2i];
    float4 cur3 = (t < 16) ? bp[s3i] : make_float4(0, 0, 0, 0);

    for (int cc = 0; cc < CG; ++cc) {
        float4 nx0, nx1, nx2, nx3;
        if (cc < CG - 1) {  // issue next-plane loads early; they fly during the reduce
            const float4* nb = (const float4*)(base + (size_t)(cc + 1) * HW_);
            nx0 = nb[s0]; nx1 = nb[s1i]; nx2 = nb[s2i];
            if (t < 16) nx3 = nb[s3i];
        }
        // stage current plane into LDS for row/col pools
        *(float4*)&smem[ad0] = cur0;
        *(float4*)&smem[ad1] = cur1;
        *(float4*)&smem[ad2] = cur2;
        if (t < 16) *(float4*)&smem[ad3] = cur3;
        // c-pool accumulate in registers (same data, no extra reads)
        mx0 = f4max(mx0, cur0); su0 = f4add(su0, cur0);
        mx1 = f4max(mx1, cur1); su1 = f4add(su1, cur1);
        mx2 = f4max(mx2, cur2); su2 = f4add(su2, cur2);
        if (t < 16) { mx3 = f4max(mx3, cur3); su3 = f4add(su3, cur3); }
        __syncthreads();

        const int c = c0 + cc;
        if (t < 224) {
            const int q = t & 3;
            {   // row phase: reduce over w for row h = t>>2 ; w = q+4j (2-way banks, free)
                const int h = t >> 2;
                float m = -INFINITY, s = 0.f;
#pragma unroll
                for (int j = 0; j < 14; ++j) {
                    float v = smem[h * LDSW + q + 4 * j];
                    m = fmaxf(m, v); s += v;
                }
                m = fmaxf(m, __shfl_down(m, 1)); s += __shfl_down(s, 1);
                m = fmaxf(m, __shfl_down(m, 2)); s += __shfl_down(s, 2);
                if (q == 0) {
                    P2[(((size_t)b * 2 + 0) * H_ + h) * C_ + c] = m;
                    P2[(((size_t)b * 2 + 1) * H_ + h) * C_ + c] = s * (1.f / 56.f);
                }
            }
            {   // col phase: reduce over h for col w = t>>2 ; h = q*14+j (2-way banks)
                const int w = t >> 2;
                float m = -INFINITY, s = 0.f;
#pragma unroll
                for (int j = 0; j < 14; ++j) {
                    float v = smem[(q * 14 + j) * LDSW + w];
                    m = fmaxf(m, v); s += v;
                }
                m = fmaxf(m, __shfl_down(m, 1)); s += __shfl_down(s, 1);
                m = fmaxf(m, __shfl_down(m, 2)); s += __shfl_down(s, 2);
                if (q == 0) {
                    P1[(((size_t)b * 2 + 0) * C_ + c) * W_ + w] = m;
                    P1[(((size_t)b * 2 + 1) * C_ + c) * W_ + w] = s * (1.f / 56.f);
                }
            }
        }
        __syncthreads();
        if (cc < CG - 1) {
            cur0 = nx0; cur1 = nx1; cur2 = nx2;
            if (t < 16) cur3 = nx3;
        }
    }
    // write this group's c-pool partial (max, raw sum over CG channels), float4 coalesced
    float4* Pm = (float4*)(P3p + ((size_t)(b * NGRP + g) * 2 + 0) * HW_);
    float4* Ps = (float4*)(P3p + ((size_t)(b * NGRP + g) * 2 + 1) * HW_);
    Pm[s0] = mx0; Pm[s1i] = mx1; Pm[s2i] = mx2;
    Ps[s0] = su0; Ps[s1i] = su1; Ps[s2i] = su2;
    if (t < 16) { Pm[s3i] = mx3; Ps[s3i] = su3; }
}

// ---------------- Kernel 2: fold 32 group-partials into final max/mean planes ----------------
// grid = B_*HW_/256 = 392 blocks. Fully coalesced (consecutive t -> consecutive hw).
__global__ __launch_bounds__(256) void combine_p3(const float* __restrict__ P3p,
                                                  float* __restrict__ P3) {  // [B][2][HW]
    const int idx = blockIdx.x * 256 + threadIdx.x;   // b*HW + hw
    const int b = idx / HW_;
    const int hw = idx - b * HW_;
    const float* src = P3p + (size_t)b * NGRP * 2 * HW_ + hw;
    float m = -INFINITY, s = 0.f;
#pragma unroll
    for (int gg = 0; gg < NGRP; ++gg) {
        m = fmaxf(m, src[(size_t)(2 * gg + 0) * HW_]);
        s += src[(size_t)(2 * gg + 1) * HW_];
    }
    P3[((size_t)b * 2 + 0) * HW_ + hw] = m;
    P3[((size_t)b * 2 + 1) * HW_ + hw] = s * (1.f / 256.f);
}

// ---------------- Kernel 3: all three 7x7 conv+BN+sigmoid, uniform 2-channel path ----------------
// grid: (56, B, 3). branch k = blockIdx.z.
__global__ __launch_bounds__(256) void conv_all(const float* __restrict__ P1,
                                                const float* __restrict__ P2,
                                                const float* __restrict__ P3,
                                                const float* __restrict__ w_ch,
                                                const float* __restrict__ w_cw,
                                                const float* __restrict__ w_hw,
                                                const float* __restrict__ gamma,
                                                const float* __restrict__ beta,
                                                const float* __restrict__ mean,
                                                const float* __restrict__ var,
                                                float* __restrict__ s1,
                                                float* __restrict__ s2,
                                                float* __restrict__ s3) {
    const int k = blockIdx.z;
    const float* Z; const float* wsrc; float* S; int A, D;
    if (k == 0)      { Z = P1; wsrc = w_ch; S = s1; A = C_; D = W_; }
    else if (k == 1) { Z = P2; wsrc = w_cw; S = s2; A = H_; D = C_; }
    else             { Z = P3; wsrc = w_hw; S = s3; A = H_; D = W_; }

    __shared__ float wl[98];
    const int t = threadIdx.x;
    if (t < 98) wl[t] = wsrc[t];
    __syncthreads();

    const int b = blockIdx.y;
    const int AD = A * D;
    const int idx = blockIdx.x * 256 + t;
    if (idx >= AD) return;
    const int a = idx / D;
    const int d = idx - a * D;

    const float* Z0 = Z + (size_t)b * 2 * AD;
    float acc = 0.f;
#pragma unroll
    for (int dy = 0; dy < 7; ++dy) {
        int aa = a + dy - 3;
        if (aa < 0 || aa >= A) continue;
#pragma unroll
        for (int dx = 0; dx < 7; ++dx) {
            int dd = d + dx - 3;
            if (dd < 0 || dd >= D) continue;
            acc += Z0[aa * D + dd] * wl[dy * 7 + dx]
                 + Z0[AD + aa * D + dd] * wl[49 + dy * 7 + dx];
        }
    }
    float y = (acc - mean[k]) * rsqrtf(var[k] + 1e-5f) * gamma[k] + beta[k];
    S[(size_t)b * AD + idx] = 1.f / (1.f + expf(-y));
}

// ---------------- Kernel 4: out = x * (s1 + s2 + s3) / 3 ----------------
__global__ __launch_bounds__(256) void final_mul(const float* __restrict__ x,
                                                 const float* __restrict__ s1,  // [B][C][W]
                                                 const float* __restrict__ s2,  // [B][H][C]
                                                 const float* __restrict__ s3,  // [B][H][W]
                                                 float* __restrict__ out) {
    const int vid = blockIdx.x * 256 + threadIdx.x;
    const int p = vid / 784;
    const int r = vid - p * 784;
    const int h = r / 14;
    const int w4 = (r - h * 14) << 2;
    const int b = p >> 8;
    const int c = p & 255;

    const size_t xoff = (size_t)p * HW_ + h * 56 + w4;
    const float4 xv = *(const float4*)(x + xoff);
    const float4 s1v = *(const float4*)(s1 + ((size_t)(b * C_ + c)) * W_ + w4);
    const float s2s = s2[((size_t)b * H_ + h) * C_ + c];
    const float4 s3v = *(const float4*)(s3 + ((size_t)b * H_ + h) * W_ + w4);

    float4 o;
    o.x = xv.x * (s1v.x + s2s + s3v.x) * (1.f / 3.f);
    o.y = xv.y * (s1v.y + s2s + s3v.y) * (1.f / 3.f);
    o.z = xv.z * (s1v.z + s2s + s3v.z) * (1.f / 3.f);
    o.w = xv.w * (s1v.w + s2s + s3v.w) * (1.f / 3.f);
    *(float4*)(out + xoff) = o;
}

extern "C" void kernel_launch(void* const* d_in, const int* in_sizes, int n_in,
                              void* d_out, int out_size, void* d_ws, size_t ws_size,
                              hipStream_t stream) {
    const float* x = (const float*)d_in[0];
    const float* w_ch = (const float*)d_in[1];
    const float* w_cw = (const float*)d_in[2];
    const float* w_hw = (const float*)d_in[3];
    const float* gamma = (const float*)d_in[4];
    const float* beta = (const float*)d_in[5];
    const float* mean = (const float*)d_in[6];
    const float* var = (const float*)d_in[7];
    float* out = (float*)d_out;

    float* ws = (float*)d_ws;
    float* P1 = ws;               // [B][2][C][W]        = 917504
    float* P2 = P1 + 917504;      // [B][2][H][C]        = 917504
    float* P3p = P2 + 917504;     // [B][NGRP][2][HW]    = 6422528
    float* P3 = P3p + 6422528;    // [B][2][HW]          = 200704
    float* s1 = P3 + 200704;      // [B][C][W]           = 458752
    float* s2 = s1 + 458752;      // [B][H][C]           = 458752
    float* s3 = s2 + 458752;      // [B][HW]             = 100352
    // total ~37.9 MB

    pool_fused<<<B_ * NGRP, 256, 0, stream>>>(x, P1, P2, P3p);
    combine_p3<<<(B_ * HW_) / 256, 256, 0, stream>>>(P3p, P3);
    conv_all<<<dim3(56, B_, 3), 256, 0, stream>>>(P1, P2, P3, w_ch, w_cw, w_hw,
                                                  gamma, beta, mean, var, s1, s2, s3);
    final_mul<<<(B_ * C_ * HW_) / 4 / 256, 256, 0, stream>>>(x, s1, s2, s3, out);
}

// Round 3
// 262.076 us; speedup vs baseline: 1.0136x; 1.0136x over previous
//
#include <hip/hip_runtime.h>
#include <math.h>

// TripletAttention. x:[32,256,56,56] f32.
// out[b,c,h,w] = x * (s1[b,c,w] + s2[b,h,c] + s3[b,h,w]) / 3

#define B_ 32
#define C_ 256
#define H_ 56
#define W_ 56
#define HW_ 3136
#define LDSW 60            // padded LDS row stride (words); %4==0 keeps float4 stores aligned
#define CG 16              // channels per pool block
#define NGRP (C_ / CG)     // 16 channel-groups

__device__ __forceinline__ float4 f4max(float4 a, float4 b) {
    return make_float4(fmaxf(a.x, b.x), fmaxf(a.y, b.y), fmaxf(a.z, b.z), fmaxf(a.w, b.w));
}
__device__ __forceinline__ float4 f4add(float4 a, float4 b) {
    return make_float4(a.x + b.x, a.y + b.y, a.z + b.z, a.w + b.w);
}

// ---------------- Kernel 1: single pass over x ----------------
// grid = B_*NGRP = 512 blocks of 256. Each block streams CG=16 planes of one (b, c-group):
//   - per plane: stage to LDS -> row pool (P2) + col pool (P1)
//   - across planes: register max/sum accumulators -> one c-pool partial (P3p)
// Next plane's loads are issued before the current plane's reduce so HBM latency
// hides under the LDS phase.
__global__ __launch_bounds__(256) void pool_fused(const float* __restrict__ x,
                                                  float* __restrict__ P1,    // [B][2][C][W]
                                                  float* __restrict__ P2,    // [B][2][H][C]
                                                  float* __restrict__ P3p) { // [B][NGRP][2][HW]
    __shared__ float smem[H_ * LDSW];
    const int t = threadIdx.x;
    const int b = blockIdx.x >> 4;            // / NGRP
    const int g = blockIdx.x & (NGRP - 1);
    const int c0 = g * CG;
    const float* __restrict__ base = x + (size_t)(b * C_ + c0) * HW_;

    // float4-slot ownership: t, t+256, t+512, (t<16: t+768); 784 slots = one plane.
    const int s0 = t, s1i = t + 256, s2i = t + 512, s3i = t + 768;
    const int h0 = s0 / 14,  ad0 = h0 * LDSW + (s0 - h0 * 14) * 4;
    const int h1 = s1i / 14, ad1 = h1 * LDSW + (s1i - h1 * 14) * 4;
    const int h2 = s2i / 14, ad2 = h2 * LDSW + (s2i - h2 * 14) * 4;
    const int h3 = s3i / 14, ad3 = h3 * LDSW + (s3i - h3 * 14) * 4;

    float4 mx0, mx1, mx2, mx3, su0, su1, su2, su3;
    mx0 = mx1 = mx2 = mx3 = make_float4(-INFINITY, -INFINITY, -INFINITY, -INFINITY);
    su0 = su1 = su2 = su3 = make_float4(0.f, 0.f, 0.f, 0.f);

    const float4* bp = (const float4*)base;
    float4 cur0 = bp[s0], cur1 = bp[s1i], cur2 = bp[s2i];
    float4 cur3 = (t < 16) ? bp[s3i] : make_float4(0, 0, 0, 0);

    for (int cc = 0; cc < CG; ++cc) {
        float4 nx0, nx1, nx2, nx3;
        if (cc < CG - 1) {  // issue next-plane loads early; they fly during the reduce
            const float4* nb = (const float4*)(base + (size_t)(cc + 1) * HW_);
            nx0 = nb[s0]; nx1 = nb[s1i]; nx2 = nb[s2i];
            if (t < 16) nx3 = nb[s3i];
        }
        // stage current plane into LDS for row/col pools
        *(float4*)&smem[ad0] = cur0;
        *(float4*)&smem[ad1] = cur1;
        *(float4*)&smem[ad2] = cur2;
        if (t < 16) *(float4*)&smem[ad3] = cur3;
        // c-pool accumulate in registers (same data, no extra reads)
        mx0 = f4max(mx0, cur0); su0 = f4add(su0, cur0);
        mx1 = f4max(mx1, cur1); su1 = f4add(su1, cur1);
        mx2 = f4max(mx2, cur2); su2 = f4add(su2, cur2);
        if (t < 16) { mx3 = f4max(mx3, cur3); su3 = f4add(su3, cur3); }
        __syncthreads();

        const int c = c0 + cc;
        if (t < 224) {
            const int q = t & 3;
            {   // row phase: reduce over w for row h = t>>2 ; w = q+4j (2-way banks, free)
                const int h = t >> 2;
                float m = -INFINITY, s = 0.f;
#pragma unroll
                for (int j = 0; j < 14; ++j) {
                    float v = smem[h * LDSW + q + 4 * j];
                    m = fmaxf(m, v); s += v;
                }
                m = fmaxf(m, __shfl_down(m, 1)); s += __shfl_down(s, 1);
                m = fmaxf(m, __shfl_down(m, 2)); s += __shfl_down(s, 2);
                if (q == 0) {
                    P2[(((size_t)b * 2 + 0) * H_ + h) * C_ + c] = m;
                    P2[(((size_t)b * 2 + 1) * H_ + h) * C_ + c] = s * (1.f / 56.f);
                }
            }
            {   // col phase: reduce over h for col w = t>>2 ; h = q*14+j (2-way banks)
                const int w = t >> 2;
                float m = -INFINITY, s = 0.f;
#pragma unroll
                for (int j = 0; j < 14; ++j) {
                    float v = smem[(q * 14 + j) * LDSW + w];
                    m = fmaxf(m, v); s += v;
                }
                m = fmaxf(m, __shfl_down(m, 1)); s += __shfl_down(s, 1);
                m = fmaxf(m, __shfl_down(m, 2)); s += __shfl_down(s, 2);
                if (q == 0) {
                    P1[(((size_t)b * 2 + 0) * C_ + c) * W_ + w] = m;
                    P1[(((size_t)b * 2 + 1) * C_ + c) * W_ + w] = s * (1.f / 56.f);
                }
            }
        }
        __syncthreads();
        if (cc < CG - 1) {
            cur0 = nx0; cur1 = nx1; cur2 = nx2;
            if (t < 16) cur3 = nx3;
        }
    }
    // write this group's c-pool partial (max, raw sum over CG channels), float4 coalesced
    float4* Pm = (float4*)(P3p + ((size_t)(b * NGRP + g) * 2 + 0) * HW_);
    float4* Ps = (float4*)(P3p + ((size_t)(b * NGRP + g) * 2 + 1) * HW_);
    Pm[s0] = mx0; Pm[s1i] = mx1; Pm[s2i] = mx2;
    Ps[s0] = su0; Ps[s1i] = su1; Ps[s2i] = su2;
    if (t < 16) { Pm[s3i] = mx3; Ps[s3i] = su3; }
}

// ---------------- Kernel 2: all three 7x7 conv+BN+sigmoid ----------------
// grid: (56, B, 3). branch k = blockIdx.z.
// Branch 2 inlines the NGRP-partial fold into an LDS halo tile, then convolves from LDS
// (no separate combine dispatch, no P3 buffer).
__global__ __launch_bounds__(256) void conv_all(const float* __restrict__ P1,
                                                const float* __restrict__ P2,
                                                const float* __restrict__ P3p,
                                                const float* __restrict__ w_ch,
                                                const float* __restrict__ w_cw,
                                                const float* __restrict__ w_hw,
                                                const float* __restrict__ gamma,
                                                const float* __restrict__ beta,
                                                const float* __restrict__ mean,
                                                const float* __restrict__ var,
                                                float* __restrict__ s1,
                                                float* __restrict__ s2,
                                                float* __restrict__ s3) {
    __shared__ float wl[98];
    __shared__ float zmax[12 * 56];   // halo tile: <=12 rows of combined max
    __shared__ float zmean[12 * 56];  // halo tile: combined mean
    const int k = blockIdx.z;
    const int t = threadIdx.x;
    const int b = blockIdx.y;
    const float* wsrc = (k == 0) ? w_ch : (k == 1) ? w_cw : w_hw;
    if (t < 98) wl[t] = wsrc[t];

    if (k == 2) {
        if (blockIdx.x >= 13) return;               // 3136/256 = 12.25 -> 13 blocks per b
        const int i0 = blockIdx.x * 256;
        const int alo = max(0, i0 / 56 - 3);
        const int ahi = min(55, (i0 + 255) / 56 + 3);
        const int nrows = ahi - alo + 1;            // <= 12
        const float* src = P3p + (size_t)b * (NGRP * 2 * HW_);
        for (int p = t; p < nrows * 56; p += 256) {
            const int r = p / 56;
            const int pos = (alo + r) * 56 + (p - r * 56);
            float m = -INFINITY, s = 0.f;
#pragma unroll
            for (int g = 0; g < NGRP; ++g) {
                m = fmaxf(m, src[(size_t)(2 * g + 0) * HW_ + pos]);
                s += src[(size_t)(2 * g + 1) * HW_ + pos];
            }
            zmax[p] = m; zmean[p] = s * (1.f / 256.f);
        }
        __syncthreads();
        const int idx = i0 + t;
        if (idx < HW_) {
            const int a = idx / 56, d = idx - a * 56;
            float acc = 0.f;
#pragma unroll
            for (int dy = 0; dy < 7; ++dy) {
                int aa = a + dy - 3;
                if (aa < 0 || aa >= 56) continue;
                const float* zm = &zmax[(aa - alo) * 56];
                const float* zs = &zmean[(aa - alo) * 56];
#pragma unroll
                for (int dx = 0; dx < 7; ++dx) {
                    int dd = d + dx - 3;
                    if (dd < 0 || dd >= 56) continue;
                    acc += zm[dd] * wl[dy * 7 + dx] + zs[dd] * wl[49 + dy * 7 + dx];
                }
            }
            float y = (acc - mean[2]) * rsqrtf(var[2] + 1e-5f) * gamma[2] + beta[2];
            s3[(size_t)b * HW_ + idx] = 1.f / (1.f + expf(-y));
        }
        return;
    }

    __syncthreads();
    const float* Z; float* S; int A, D;
    if (k == 0) { Z = P1; S = s1; A = C_; D = W_; }
    else        { Z = P2; S = s2; A = H_; D = C_; }

    const int AD = A * D;
    const int idx = blockIdx.x * 256 + t;
    if (idx >= AD) return;
    const int a = idx / D;
    const int d = idx - a * D;

    const float* Z0 = Z + (size_t)b * 2 * AD;
    float acc = 0.f;
#pragma unroll
    for (int dy = 0; dy < 7; ++dy) {
        int aa = a + dy - 3;
        if (aa < 0 || aa >= A) continue;
#pragma unroll
        for (int dx = 0; dx < 7; ++dx) {
            int dd = d + dx - 3;
            if (dd < 0 || dd >= D) continue;
            acc += Z0[aa * D + dd] * wl[dy * 7 + dx]
                 + Z0[AD + aa * D + dd] * wl[49 + dy * 7 + dx];
        }
    }
    float y = (acc - mean[k]) * rsqrtf(var[k] + 1e-5f) * gamma[k] + beta[k];
    S[(size_t)b * AD + idx] = 1.f / (1.f + expf(-y));
}

// ---------------- Kernel 3: out = x * (s1 + s2 + s3) / 3 ----------------
__global__ __launch_bounds__(256) void final_mul(const float* __restrict__ x,
                                                 const float* __restrict__ s1,  // [B][C][W]
                                                 const float* __restrict__ s2,  // [B][H][C]
                                                 const float* __restrict__ s3,  // [B][H][W]
                                                 float* __restrict__ out) {
    const int vid = blockIdx.x * 256 + threadIdx.x;
    const int p = vid / 784;
    const int r = vid - p * 784;
    const int h = r / 14;
    const int w4 = (r - h * 14) << 2;
    const int b = p >> 8;
    const int c = p & 255;

    const size_t xoff = (size_t)p * HW_ + h * 56 + w4;
    const float4 xv = *(const float4*)(x + xoff);
    const float4 s1v = *(const float4*)(s1 + ((size_t)(b * C_ + c)) * W_ + w4);
    const float s2s = s2[((size_t)b * H_ + h) * C_ + c];
    const float4 s3v = *(const float4*)(s3 + ((size_t)b * H_ + h) * W_ + w4);

    float4 o;
    o.x = xv.x * (s1v.x + s2s + s3v.x) * (1.f / 3.f);
    o.y = xv.y * (s1v.y + s2s + s3v.y) * (1.f / 3.f);
    o.z = xv.z * (s1v.z + s2s + s3v.z) * (1.f / 3.f);
    o.w = xv.w * (s1v.w + s2s + s3v.w) * (1.f / 3.f);
    *(float4*)(out + xoff) = o;
}

extern "C" void kernel_launch(void* const* d_in, const int* in_sizes, int n_in,
                              void* d_out, int out_size, void* d_ws, size_t ws_size,
                              hipStream_t stream) {
    const float* x = (const float*)d_in[0];
    const float* w_ch = (const float*)d_in[1];
    const float* w_cw = (const float*)d_in[2];
    const float* w_hw = (const float*)d_in[3];
    const float* gamma = (const float*)d_in[4];
    const float* beta = (const float*)d_in[5];
    const float* mean = (const float*)d_in[6];
    const float* var = (const float*)d_in[7];
    float* out = (float*)d_out;

    float* ws = (float*)d_ws;
    float* P1 = ws;               // [B][2][C][W]        = 917504
    float* P2 = P1 + 917504;      // [B][2][H][C]        = 917504
    float* P3p = P2 + 917504;     // [B][NGRP][2][HW]    = 3211264 (12.8 MB)
    float* s1 = P3p + 3211264;    // [B][C][W]           = 458752
    float* s2 = s1 + 458752;      // [B][H][C]           = 458752
    float* s3 = s2 + 458752;      // [B][HW]             = 100352
    // total ~24.3 MB

    pool_fused<<<B_ * NGRP, 256, 0, stream>>>(x, P1, P2, P3p);
    conv_all<<<dim3(56, B_, 3), 256, 0, stream>>>(P1, P2, P3p, w_ch, w_cw, w_hw,
                                                  gamma, beta, mean, var, s1, s2, s3);
    final_mul<<<(B_ * C_ * HW_) / 4 / 256, 256, 0, stream>>>(x, s1, s2, s3, out);
}